// Round 6
// baseline (178.358 us; speedup 1.0000x reference)
//
#include <hip/hip_runtime.h>
#include <cmath>

#define NN 8192
#define DD 512
#define NSRC 8
#define PSW 8                  // ps partials per row = 8 column groups
#define COFF 100.0f            // fixed softmax offset

typedef __bf16 bf16x8 __attribute__((ext_vector_type(8)));
typedef float  f32x4  __attribute__((ext_vector_type(4)));
typedef float  f32x16 __attribute__((ext_vector_type(16)));

__device__ __forceinline__ unsigned short f2bf(float f) {
    unsigned u = __float_as_uint(f);
    u += 0x7fffu + ((u >> 16) & 1u);
    return (unsigned short)(u >> 16);
}

// ---------------------------------------------------------------------------
// Kernel A: blocks 0..127 per-source text sums; blocks 128+ cast fp32->bf16.
// ---------------------------------------------------------------------------
__global__ __launch_bounds__(256) void k_prep(
    const float* __restrict__ img, const float* __restrict__ txt,
    const int* __restrict__ labels,
    unsigned short* __restrict__ imgB, unsigned short* __restrict__ txtB,
    float* __restrict__ Tsum, int* __restrict__ counts)
{
    const int tid = threadIdx.x;
    if (blockIdx.x >= 128) {
        const size_t gid = (size_t)(blockIdx.x - 128) * 256 + tid;
        const size_t half = (size_t)NN * DD / 8;
        const float* src = (gid < half) ? img : txt;
        unsigned short* dst = (gid < half) ? imgB : txtB;
        const size_t off = ((gid < half) ? gid : gid - half) * 8;
        const float4 v0 = *(const float4*)(src + off);
        const float4 v1 = *(const float4*)(src + off + 4);
        union { unsigned short s[8]; uint4 v; } o;
        o.s[0] = f2bf(v0.x); o.s[1] = f2bf(v0.y); o.s[2] = f2bf(v0.z); o.s[3] = f2bf(v0.w);
        o.s[4] = f2bf(v1.x); o.s[5] = f2bf(v1.y); o.s[6] = f2bf(v1.z); o.s[7] = f2bf(v1.w);
        *(uint4*)(dst + off) = o.v;
        return;
    }
    __shared__ float Tacc[NSRC * DD];
    __shared__ int cacc[NSRC];
    const int d0 = 2 * tid;
#pragma unroll
    for (int s = 0; s < NSRC; s++) {
        Tacc[s * DD + d0] = 0.f;
        Tacc[s * DD + d0 + 1] = 0.f;
    }
    if (tid < NSRC) cacc[tid] = 0;
    __syncthreads();

    const int row0 = blockIdx.x * 64;
    if (tid < 64) atomicAdd(&cacc[labels[row0 + tid]], 1);

    for (int j = 0; j < 64; j++) {
        const int lab = labels[row0 + j];
        const float2 v = *(const float2*)(txt + (size_t)(row0 + j) * DD + d0);
        Tacc[lab * DD + d0]     += v.x;
        Tacc[lab * DD + d0 + 1] += v.y;
    }
    __syncthreads();
#pragma unroll
    for (int k = 0; k < NSRC * DD / 256; k++) {
        const int e = k * 256 + tid;
        atomicAdd(&Tsum[e], Tacc[e]);
    }
    if (tid < NSRC) atomicAdd(&counts[tid], cacc[tid]);
}

// ---------------------------------------------------------------------------
// Kernel B (R6): persistent 256-block GEMM switched to 32x32x16 MFMA.
// Motivation (R5 post-mortem): phase = serial LDS(772) + MFMA(620) cyc.
// 32x32 fragments cut LDS reads/K-tile 256->192 KB/CU and run at the higher
// 32x32 MFMA rate (2066 vs 2480 cyc/tile). Wave grid 4wr x 2wc, per-wave
// 64 rows x 128 cols, acc[2][4] f32x16. Per K-tile: 4 phases (jh,kh) =
// (0,0),(1,0),(1,1),(0,1), 8 MFMA each. Register prefetch one phase ahead
// for bf (ph1->ph2, ph2->ph3, ph3->ph4) overlaps those LDS drains with MFMA.
// Stage schedule: ph1: 6 loads (A' q1q3 + B' x4), ph4: 2 loads (A'' q0q2 —
// moved from ph3: issued only after ph3's end barrier, when every wave's kh1
// A-reads are drained -> no WAR race with the in-flight prefetches).
// vmcnt(2) at ph4/ph8: outstanding = 2+6+2 = 10 -> drains exactly one tile.
// C/D layout (m74/m101): row=(reg&3)+8*(reg>>2)+4*(lane>>5), col=lane&31.
// ---------------------------------------------------------------------------
__global__ __launch_bounds__(512, 2) void k_lse_mfma256(
    const unsigned short* __restrict__ imgB, const unsigned short* __restrict__ txtB,
    const float* __restrict__ scale_p, float* __restrict__ ps)
{
    __shared__ uint4 lds[8192];            // 128 KiB
    const float scale = scale_p[0];
    const int tid  = threadIdx.x;
    const int lane = tid & 63;
    const int w    = tid >> 6;
    const int wr   = w >> 1;               // 0..3 (row quarter)
    const int wc   = w & 1;                // 0..1 (col half)
    const int lr   = lane & 31;            // row/col within 32x32 frag
    const int lh   = lane >> 5;            // k-octet half
    const int c    = blockIdx.x & 7;       // XCD (round-robin dispatch)
    const int l    = blockIdx.x >> 3;
    const int by   = c * 4 + (l >> 3);     // row panel 0..31
    const int bcg  = l & 7;                // column group 0..7
    const int row0    = by * 256;
    const int colBase = bcg * 1024;

    const int st_r  = tid >> 3;
    const int st_kc = (tid & 7) ^ (st_r & 7);

    int idxA[2], swA[2];                   // A frag bases (uint4 units)
#pragma unroll
    for (int mi = 0; mi < 2; mi++) {
        const int r = wr * 64 + mi * 32 + lr;
        idxA[mi] = r * 8; swA[mi] = r & 7;
    }
    int idxB[4], swB[4];                   // B frag bases
#pragma unroll
    for (int ji = 0; ji < 4; ji++) {
        const int r = wc * 128 + ji * 32 + lr;
        idxB[ji] = 2048 + r * 8; swB[ji] = r & 7;
    }

#define SA(BUF, Q, T)                                                          \
    { const unsigned short* g = imgB + (size_t)(row0 + (Q) * 64 + st_r) * DD   \
          + (((T) & 7) << 6) + (st_kc << 3);                                   \
      __builtin_amdgcn_global_load_lds(                                        \
          (const __attribute__((address_space(1))) void*)g,                    \
          (__attribute__((address_space(3))) void*)                            \
              &lds[(BUF) * 4096 + (Q) * 512 + tid], 16, 0, 0); }
#define SB(BUF, Q, T)                                                          \
    { const unsigned short* g = txtB                                           \
          + (size_t)(colBase + ((((T) >> 3) & 3) << 8) + (Q) * 64 + st_r) * DD \
          + (((T) & 7) << 6) + (st_kc << 3);                                   \
      __builtin_amdgcn_global_load_lds(                                        \
          (const __attribute__((address_space(1))) void*)g,                    \
          (__attribute__((address_space(3))) void*)                            \
              &lds[(BUF) * 4096 + 2048 + (Q) * 512 + tid], 16, 0, 0); }

#define RD_AF(DST, BUF, KH)                                                    \
    _Pragma("unroll") for (int s = 0; s < 2; s++)                              \
        _Pragma("unroll") for (int mi = 0; mi < 2; mi++)                       \
            DST[mi][s] = *reinterpret_cast<const bf16x8*>(                     \
                &lds[(BUF) * 4096 + idxA[mi]                                   \
                     + ((((((KH) * 2 + s) << 1) | lh)) ^ swA[mi])]);

#define RD_BF(DST, BUF, JH, KH)                                                \
    _Pragma("unroll") for (int s = 0; s < 2; s++)                              \
        _Pragma("unroll") for (int jl = 0; jl < 2; jl++)                       \
            DST[jl][s] = *reinterpret_cast<const bf16x8*>(                     \
                &lds[(BUF) * 4096 + idxB[(JH) * 2 + jl]                        \
                     + ((((((KH) * 2 + s) << 1) | lh)) ^ swB[(JH) * 2 + jl])]);

#define MM(AF, BF, JB)                                                         \
    _Pragma("unroll") for (int s = 0; s < 2; s++)                              \
        _Pragma("unroll") for (int mi = 0; mi < 2; mi++)                       \
            _Pragma("unroll") for (int jl = 0; jl < 2; jl++)                   \
                acc[mi][(JB) + jl] = __builtin_amdgcn_mfma_f32_32x32x16_bf16(  \
                    AF[mi][s], BF[jl][s], acc[mi][(JB) + jl], 0, 0, 0);

// 4 phases of one K-tile in BUF. STG1 issued in ph1 (6 loads), STG4 in ph4
// (2 loads, after ph3's end barrier => all kh1 A-reads drained block-wide).
#define TILE4(BUF, STG1, STG4)                                                 \
    do {                                                                       \
        bf16x8 af0[2][2], af1[2][2];                                           \
        bf16x8 bf0[2][2], bfp[2][2], bfq[2][2], bfr[2][2];                     \
        /* ph1 (jh0,kh0) */                                                    \
        RD_AF(af0, BUF, 0);                                                    \
        RD_BF(bf0, BUF, 0, 0);                                                 \
        RD_BF(bfp, BUF, 1, 0);           /* prefetch ph2 */                    \
        STG1;                                                                  \
        __builtin_amdgcn_s_barrier();                                          \
        __builtin_amdgcn_s_setprio(1);                                         \
        MM(af0, bf0, 0);                                                       \
        __builtin_amdgcn_s_setprio(0);                                         \
        __builtin_amdgcn_s_barrier();                                          \
        /* ph2 (jh1,kh0) */                                                    \
        RD_BF(bfq, BUF, 1, 1);           /* prefetch ph3 */                    \
        __builtin_amdgcn_s_barrier();                                          \
        __builtin_amdgcn_s_setprio(1);                                         \
        MM(af0, bfp, 2);                                                       \
        __builtin_amdgcn_s_setprio(0);                                         \
        __builtin_amdgcn_s_barrier();                                          \
        /* ph3 (jh1,kh1) */                                                    \
        RD_AF(af1, BUF, 1);                                                    \
        RD_BF(bfr, BUF, 0, 1);           /* prefetch ph4 */                    \
        __builtin_amdgcn_s_barrier();                                          \
        __builtin_amdgcn_s_setprio(1);                                         \
        MM(af1, bfq, 2);                                                       \
        __builtin_amdgcn_s_setprio(0);                                         \
        __builtin_amdgcn_s_barrier();                                          \
        /* ph4 (jh0,kh1) */                                                    \
        STG4;                                                                  \
        __builtin_amdgcn_s_barrier();                                          \
        __builtin_amdgcn_s_setprio(1);                                         \
        MM(af1, bfr, 0);                                                       \
        __builtin_amdgcn_s_setprio(0);                                         \
        asm volatile("s_waitcnt vmcnt(2)" ::: "memory");                       \
        __builtin_amdgcn_s_barrier();                                          \
    } while (0)

    // ---- prologue: tile 0 fully + tile 1 Aq0,Aq2 (plays "prev ph4/8") ----
#pragma unroll
    for (int q = 0; q < 4; q++) SA(0, q, 0);
#pragma unroll
    for (int q = 0; q < 4; q++) SB(0, q, 0);
    SA(1, 0, 1); SA(1, 2, 1);
    asm volatile("s_waitcnt vmcnt(2)" ::: "memory");   // tile 0 landed
    __builtin_amdgcn_s_barrier();

    f32x16 acc[2][4];
    f32x16 s_run[2];
#pragma unroll
    for (int mi = 0; mi < 2; mi++) {
        s_run[mi] = (f32x16)(0.f);
#pragma unroll
        for (int ji = 0; ji < 4; ji++) acc[mi][ji] = (f32x16)(0.f);
    }

#pragma unroll 1
    for (int v0 = 0; v0 < 32; v0 += 2) {
        TILE4(0,
              SA(1, 1, v0 + 1); SA(1, 3, v0 + 1);
              SB(1, 0, v0 + 1); SB(1, 1, v0 + 1);
              SB(1, 2, v0 + 1); SB(1, 3, v0 + 1),
              SA(0, 0, v0 + 2); SA(0, 2, v0 + 2));
        TILE4(1,
              SA(0, 1, v0 + 2); SA(0, 3, v0 + 2);
              SB(0, 0, v0 + 2); SB(0, 1, v0 + 2);
              SB(0, 2, v0 + 2); SB(0, 3, v0 + 2),
              SA(1, 0, v0 + 3); SA(1, 2, v0 + 3));
        if ((v0 & 6) == 6) {
            // ct boundary: register-only exp flush (no barrier, no loads)
#pragma unroll
            for (int mi = 0; mi < 2; mi++) {
#pragma unroll
                for (int rg = 0; rg < 16; rg++) {
                    float es = s_run[mi][rg];
#pragma unroll
                    for (int ji = 0; ji < 4; ji++)
                        es += __expf(fmaf(acc[mi][ji][rg], scale, -COFF));
                    s_run[mi][rg] = es;
                }
#pragma unroll
                for (int ji = 0; ji < 4; ji++) acc[mi][ji] = (f32x16)(0.f);
            }
        }
    }

    asm volatile("s_waitcnt vmcnt(0)" ::: "memory");
    __syncthreads();

    // ---- epilogue: col-reduce each row (32 cols in-frag), fold 2 wc ----
    float* fred = (float*)lds;             // 256 rows x 2 wc floats
#pragma unroll
    for (int mi = 0; mi < 2; mi++) {
#pragma unroll
        for (int rg = 0; rg < 16; rg++) {
            float es = s_run[mi][rg];
#pragma unroll
            for (int off = 1; off <= 16; off <<= 1) es += __shfl_xor(es, off);
            if (lr == 0) {
                const int rloc = wr * 64 + mi * 32 + (rg & 3) + 8 * (rg >> 2) + 4 * lh;
                fred[rloc * 2 + wc] = es;
            }
        }
    }
    __syncthreads();
    if (tid < 256) {
        const float tot = fred[tid * 2] + fred[tid * 2 + 1];
        ps[(size_t)(row0 + tid) * PSW + bcg] = tot;
    }
#undef SA
#undef SB
#undef RD_AF
#undef RD_BF
#undef MM
#undef TILE4
}

// ---------------------------------------------------------------------------
// Kernel C: combine partials -> lse, per-row fp32 dot products, reduce.
// ---------------------------------------------------------------------------
__global__ __launch_bounds__(256) void k_finalize(
    const float* __restrict__ img, const float* __restrict__ txt,
    const int* __restrict__ labels, const float* __restrict__ scale_p,
    const float* __restrict__ Tsum, const int* __restrict__ counts,
    const float* __restrict__ ps,
    float* __restrict__ out)
{
    const float scale = scale_p[0];
    const int tid = threadIdx.x;
    const int lane = tid & 63;
    const int wave = tid >> 6;
    const int rowBase = blockIdx.x * 16 + wave * 4;
    float local = 0.f;
#pragma unroll
    for (int it = 0; it < 4; it++) {
        const int i = rowBase + it;
        const int lab = labels[i];
        float ds = 0.f, dt = 0.f;
        const float* ip = img + (size_t)i * DD;
        const float* tp = txt + (size_t)i * DD;
        const float* sp = Tsum + lab * DD;
#pragma unroll
        for (int k = lane; k < DD; k += 64) {
            const float a = ip[k];
            ds = fmaf(a, tp[k], ds);
            dt = fmaf(a, sp[k], dt);
        }
        float es = (lane < PSW) ? ps[(size_t)i * PSW + lane] : 0.f;
#pragma unroll
        for (int off = 32; off; off >>= 1) {
            ds += __shfl_xor(ds, off);
            dt += __shfl_xor(dt, off);
            es += __shfl_xor(es, off);
        }
        if (lane == 0) {
            const float lse = COFF + __logf(es);
            const int cnt = counts[lab] - 1;
            if (cnt > 0) {
                const float row_sum = scale * (dt - ds) - (float)cnt * lse;
                local += row_sum / (float)cnt;
            }
        }
    }
    __shared__ float red[4];
    if (lane == 0) red[wave] = local;
    __syncthreads();
    if (tid == 0) {
        const float t = red[0] + red[1] + red[2] + red[3];
        atomicAdd(out, -t / (float)NN);
    }
}

// ---------------------------------------------------------------------------
extern "C" void kernel_launch(void* const* d_in, const int* in_sizes, int n_in,
                              void* d_out, int out_size, void* d_ws, size_t ws_size,
                              hipStream_t stream)
{
    const float* img     = (const float*)d_in[0];
    const float* txt     = (const float*)d_in[1];
    const float* scale_p = (const float*)d_in[2];
    const int*   labels  = (const int*)d_in[3];
    float* out = (float*)d_out;

    char* ws = (char*)d_ws;
    float* ps    = (float*)(ws);                                  // 256 KB (8192 x 8)
    float* Tsum  = (float*)(ws + (1 << 18));                      // 16 KB
    int*   counts = (int*)(ws + (1 << 18) + NSRC * DD * 4);
    unsigned short* imgB = (unsigned short*)(ws + 2 * 1024 * 1024);   // 8 MB
    unsigned short* txtB = (unsigned short*)(ws + 10 * 1024 * 1024);  // 8 MB

    hipMemsetAsync(ws + (1 << 18), 0, NSRC * DD * 4 + 64, stream);  // Tsum+counts
    hipMemsetAsync(d_out, 0, 4, stream);                            // out

    k_prep<<<128 + (2 * NN * DD / 8) / 256, 256, 0, stream>>>(
        img, txt, labels, imgB, txtB, Tsum, counts);
    k_lse_mfma256<<<256, 512, 0, stream>>>(imgB, txtB, scale_p, ps);
    k_finalize<<<NN / 16, 256, 0, stream>>>(img, txt, labels, scale_p,
                                            Tsum, counts, ps, out);
}